// Round 8
// baseline (41.974 us; speedup 1.0000x reference)
//
#include <hip/hip_runtime.h>

#define NN 2048
#define HALF 16777216ull              // B*N*N = 4*2048*2048
#define MLP_BLOCKS 256                // 32 rows each

typedef float  __attribute__((ext_vector_type(4))) f32x4;
typedef short  __attribute__((ext_vector_type(8))) s16x8;
typedef ushort __attribute__((ext_vector_type(4))) u16x4;

// fp32 -> bf16 (RTNE)
__device__ __forceinline__ ushort f2bf(float f) {
    union { float f; uint32_t u; } v; v.f = f;
    const uint32_t r = v.u + 0x7FFFu + ((v.u >> 16) & 1u);
    return (ushort)(r >> 16);
}

// ---------------- K1: weight transpose -> bf16 ----------------
__global__ __launch_bounds__(256) void k1_transpose(
    const float* __restrict__ Wmu1, const float* __restrict__ Wmu2,
    ushort* __restrict__ w1t, ushort* __restrict__ w2t)
{
    const int e = blockIdx.x * 256 + threadIdx.x;   // 0..98303
    if (e < 32768) {
        const int k = e >> 8, n = e & 255;
        w1t[n * 128 + k] = f2bf(Wmu1[e]);
    } else {
        const int e2 = e - 32768;
        const int k = e2 >> 8, n = e2 & 255;
        w2t[n * 256 + k] = f2bf(Wmu2[e2]);
    }
}

// ---------------- K2: {MFMA MLP -> shift} | {idx fill} ----------------
// blocks [0,256):    shift[row] for 32 rows (to d_ws) — no bulk writes
// blocks [256,2304): out[HALF + row*NN + j] = (float)j  (4 rows each, 64 MiB)
__global__ __launch_bounds__(256) void k2_mlp_idx(
    const float* __restrict__ x,
    const ushort* __restrict__ w1t, const float* __restrict__ bmu1,
    const ushort* __restrict__ w2t, const float* __restrict__ bmu2,
    const float* __restrict__ Wkp,  const float* __restrict__ bkp,
    float* __restrict__ out, float* __restrict__ shift)
{
    __shared__ ushort xs[32 * 136];   // x rows bf16, stride 136
    __shared__ ushort h1[32 * 264];   // h1 rows bf16, stride 264
    __shared__ float  red[4][2][16];

    const int bid = blockIdx.x, t = threadIdx.x;
    const int lane = t & 63, w = t >> 6;

    if (bid >= MLP_BLOCKS) {
        const int row = (bid - MLP_BLOCKS) * 4 + w;
        float* idx = out + HALF + (size_t)row * NN;
        #pragma unroll
        for (int i = 0; i < 8; ++i) {
            const int c = i * 256 + lane * 4;
            f32x4 v = {(float)c, (float)(c + 1), (float)(c + 2), (float)(c + 3)};
            *(f32x4*)(idx + c) = v;
        }
        return;
    }

    // ---- MFMA MLP (identical math to rounds 6/7) ----
    const int l16 = lane & 15, lq = lane >> 4;
    const int row0 = bid * 32;

    {
        const int r = t >> 3, k0 = (t & 7) * 16;
        const float* src = x + (size_t)(row0 + r) * 128 + k0;
        s16x8 s0, s1;
        #pragma unroll
        for (int q = 0; q < 8; ++q) {
            s0[q] = (short)f2bf(src[q]);
            s1[q] = (short)f2bf(src[8 + q]);
        }
        *(s16x8*)&xs[r * 136 + k0]     = s0;
        *(s16x8*)&xs[r * 136 + k0 + 8] = s1;
    }
    __syncthreads();

    // layer 1: K=128 (4 chunks of 32)
    f32x4 acc[2][4] = {};
    #pragma unroll
    for (int kc = 0; kc < 4; ++kc) {
        const s16x8 b0 = *(const s16x8*)&xs[l16 * 136 + kc * 32 + lq * 8];
        const s16x8 b1 = *(const s16x8*)&xs[(16 + l16) * 136 + kc * 32 + lq * 8];
        #pragma unroll
        for (int nt = 0; nt < 4; ++nt) {
            const int ng = (w * 4 + nt) * 16 + l16;
            const s16x8 a = *(const s16x8*)(w1t + ng * 128 + kc * 32 + lq * 8);
            acc[0][nt] = __builtin_amdgcn_mfma_f32_16x16x32_bf16(a, b0, acc[0][nt], 0, 0, 0);
            acc[1][nt] = __builtin_amdgcn_mfma_f32_16x16x32_bf16(a, b1, acc[1][nt], 0, 0, 0);
        }
    }

    // bias + relu -> h1 bf16 row-major
    #pragma unroll
    for (int nt = 0; nt < 4; ++nt) {
        const int c0 = (w * 4 + nt) * 16 + lq * 4;
        const f32x4 bv = *(const f32x4*)&bmu1[c0];
        #pragma unroll
        for (int mt = 0; mt < 2; ++mt) {
            u16x4 hv;
            #pragma unroll
            for (int reg = 0; reg < 4; ++reg)
                hv[reg] = f2bf(fmaxf(acc[mt][nt][reg] + bv[reg], 0.f));
            *(u16x4*)&h1[(mt * 16 + l16) * 264 + c0] = hv;
        }
    }
    __syncthreads();

    // layer 2: K=256 (8 chunks of 32)
    f32x4 acc2[2][4] = {};
    #pragma unroll
    for (int kc = 0; kc < 8; ++kc) {
        const s16x8 b0 = *(const s16x8*)&h1[l16 * 264 + kc * 32 + lq * 8];
        const s16x8 b1 = *(const s16x8*)&h1[(16 + l16) * 264 + kc * 32 + lq * 8];
        #pragma unroll
        for (int nt = 0; nt < 4; ++nt) {
            const int ng = (w * 4 + nt) * 16 + l16;
            const s16x8 a = *(const s16x8*)(w2t + ng * 256 + kc * 32 + lq * 8);
            acc2[0][nt] = __builtin_amdgcn_mfma_f32_16x16x32_bf16(a, b0, acc2[0][nt], 0, 0, 0);
            acc2[1][nt] = __builtin_amdgcn_mfma_f32_16x16x32_bf16(a, b1, acc2[1][nt], 0, 0, 0);
        }
    }

    // (h2 + b2) . wkp, reduce
    float p0 = 0.f, p1 = 0.f;
    #pragma unroll
    for (int nt = 0; nt < 4; ++nt) {
        const int c0 = (w * 4 + nt) * 16 + lq * 4;
        const f32x4 b2 = *(const f32x4*)&bmu2[c0];
        const f32x4 wk = *(const f32x4*)&Wkp[c0];
        #pragma unroll
        for (int reg = 0; reg < 4; ++reg) {
            p0 = fmaf(acc2[0][nt][reg] + b2[reg], wk[reg], p0);
            p1 = fmaf(acc2[1][nt][reg] + b2[reg], wk[reg], p1);
        }
    }
    p0 += __shfl_xor(p0, 16, 64);  p0 += __shfl_xor(p0, 32, 64);
    p1 += __shfl_xor(p1, 16, 64);  p1 += __shfl_xor(p1, 32, 64);
    if (lane < 16) { red[w][0][lane] = p0; red[w][1][lane] = p1; }
    __syncthreads();

    if (t < 32) {
        const int mt = t >> 4, m = t & 15;
        const float s = red[0][mt][m] + red[1][mt][m] + red[2][mt][m] + red[3][mt][m];
        shift[row0 + t] = 7.0f * (s + bkp[0]) + 2.0f;   // fold the +2 here
    }
}

// ---------------- K3: adj fill (zero LDS, full occupancy) ----------------
// out[row*NN + j] = sigmoid(shift[row] - 7j)
__global__ __launch_bounds__(256) void k3_adj(
    const float* __restrict__ shift, float* __restrict__ out)
{
    const int t = threadIdx.x, lane = t & 63, w = t >> 6;
    const int row = blockIdx.x * 4 + w;
    const float s = shift[row];

    float* adj = out + (size_t)row * NN;
    #pragma unroll
    for (int i = 0; i < 8; ++i) {
        const int c = i * 256 + lane * 4;
        f32x4 a;
        #pragma unroll
        for (int q = 0; q < 4; ++q) {
            const float z = fmaf(-7.0f, (float)(c + q), s);
            a[q] = 1.0f / (1.0f + __expf(-z));
        }
        *(f32x4*)(adj + c) = a;
    }
}

extern "C" void kernel_launch(void* const* d_in, const int* in_sizes, int n_in,
                              void* d_out, int out_size, void* d_ws, size_t ws_size,
                              hipStream_t stream)
{
    (void)in_sizes; (void)n_in; (void)out_size; (void)ws_size;
    const float* x    = (const float*)d_in[0];
    // d_in[1..5] dead: softmax over size-1 axis == 1 -> edge_prob == 1/N exactly;
    // stable argsort of all-ties rows == identity permutation.
    const float* Wmu1 = (const float*)d_in[6];
    const float* bmu1 = (const float*)d_in[7];
    const float* Wmu2 = (const float*)d_in[8];
    const float* bmu2 = (const float*)d_in[9];
    const float* Wkp  = (const float*)d_in[10];
    const float* bkp  = (const float*)d_in[11];

    ushort* w1t   = (ushort*)d_ws;                          // 64 KB
    ushort* w2t   = (ushort*)((char*)d_ws + 65536);         // 128 KB
    float*  shift = (float*)((char*)d_ws + 65536 + 131072); // 32 KB
    float*  out   = (float*)d_out;

    hipLaunchKernelGGL(k1_transpose, dim3(384), dim3(256), 0, stream,
                       Wmu1, Wmu2, w1t, w2t);
    hipLaunchKernelGGL(k2_mlp_idx, dim3(MLP_BLOCKS + 2048), dim3(256), 0, stream,
                       x, w1t, bmu1, w2t, bmu2, Wkp, bkp, out, shift);
    hipLaunchKernelGGL(k3_adj, dim3(2048), dim3(256), 0, stream,
                       shift, out);
}